// Round 7
// baseline (1225.778 us; speedup 1.0000x reference)
//
#include <hip/hip_runtime.h>

#define N_NODES 100000
#define N_EDGES 3200000
#define N_GRAPHS 1000
#define NB 1024            // dst-range buckets
#define NPB 98             // nodes per bucket (1024*98 >= 100000)
#define CAP 3584           // per-bucket edge capacity (mean 3136 + 8 sigma)
#define EPB 4096           // edges per bucketing block
#define SPLIT1 2
#define SPLIT2 8
#define SPLIT3 8

// ---------------- workspace layout (element offsets, 4B units) --------------
// deg  : int  [N]        @ 0
// dinv : float[N]        @ N
// xp   : float[4N]       @ 2N    x * dinv
// t2p  : float[32N]      @ 6N    (h1@W2)*dinv   [agg3 (16N) aliases @6N later]
// t3p  : float[16N]      @ 38N   (h2@W3)*dinv   [agg1 (4N) aliases @38N first]
// agg2 : float[32N]      @ 54N
// bcnt : int  [NB]       @ 86N
// gsum : float[G]        @ 86N+NB
// gcnt : int  [G]        @ 86N+NB+G
// pay  : uint [NB*CAP]   @ 86N+NB+2G
// total = 12,273,040 elem = 49.1 MB  (< 54.9 MB proven-safe in round 2)

__global__ void k_zero(int* __restrict__ deg, int* __restrict__ bcnt,
                       float* __restrict__ gsum, int* __restrict__ gcnt,
                       float* __restrict__ agg1, float* __restrict__ agg2) {
    int i = blockIdx.x * blockDim.x + threadIdx.x;
    if (i < N_NODES) deg[i] = 0;
    if (i < 4 * N_NODES) agg1[i] = 0.0f;
    if (i < 32 * N_NODES) agg2[i] = 0.0f;
    if (i < NB) bcnt[i] = 0;
    if (i < N_GRAPHS) { gsum[i] = 0.0f; gcnt[i] = 0; }
}

__global__ void k_zero3(float* __restrict__ agg3) {
    int i = blockIdx.x * blockDim.x + threadIdx.x;
    if (i < 16 * N_NODES) agg3[i] = 0.0f;
}

// two-level bucketize: LDS histogram -> scan -> LDS place -> contiguous run flush
__global__ __launch_bounds__(256) void k_bucket(
    const int* __restrict__ src, const int* __restrict__ dst,
    int* __restrict__ deg, int* __restrict__ bcnt, unsigned* __restrict__ pay) {
    __shared__ int cnt[NB];
    __shared__ int off[NB];
    __shared__ int scanbuf[256];
    __shared__ unsigned rec[EPB];

    int tid = threadIdx.x;
    int e0 = blockIdx.x * EPB;
    for (int i = tid; i < NB; i += 256) cnt[i] = 0;
    __syncthreads();

#pragma unroll
    for (int k = 0; k < EPB / 256; ++k) {
        int e = e0 + k * 256 + tid;
        if (e < N_EDGES) {
            unsigned d = (unsigned)dst[e];
            atomicAdd(&deg[d], 1);
            atomicAdd(&cnt[d / NPB], 1);
        }
    }
    __syncthreads();

    int base = tid * 4;
    int c0 = cnt[base], c1 = cnt[base + 1], c2 = cnt[base + 2], c3 = cnt[base + 3];
    int part = c0 + c1 + c2 + c3;
    scanbuf[tid] = part;
    __syncthreads();
    for (int o = 1; o < 256; o <<= 1) {
        int v = (tid >= o) ? scanbuf[tid - o] : 0;
        __syncthreads();
        scanbuf[tid] += v;
        __syncthreads();
    }
    int ex = scanbuf[tid] - part;
    off[base]     = ex;
    off[base + 1] = ex + c0;
    off[base + 2] = ex + c0 + c1;
    off[base + 3] = ex + c0 + c1 + c2;
    __syncthreads();

#pragma unroll
    for (int k = 0; k < EPB / 256; ++k) {
        int e = e0 + k * 256 + tid;
        if (e < N_EDGES) {
            unsigned s = (unsigned)src[e];
            unsigned d = (unsigned)dst[e];
            unsigned b = d / NPB;
            unsigned ld = d - b * NPB;
            int p = atomicAdd(&off[b], 1);
            rec[p] = s | (ld << 17);
        }
    }
    __syncthreads();

    for (int b = tid; b < NB; b += 256) {
        int c = cnt[b];
        if (c == 0) continue;
        int ls = off[b] - c;
        int gb = atomicAdd(&bcnt[b], c);
        unsigned* dstp = pay + (size_t)b * CAP;
        for (int k = 0; k < c; ++k) {
            int gp = gb + k;
            if (gp < CAP) dstp[gp] = rec[ls + k];
        }
    }
}

__global__ void k_prep(const float* __restrict__ x, const int* __restrict__ deg,
                       float* __restrict__ dinv, float* __restrict__ xp) {
    int n = blockIdx.x * blockDim.x + threadIdx.x;
    if (n >= N_NODES) return;
    float di = rsqrtf((float)(deg[n] + 1));
    dinv[n] = di;
    float4 v = reinterpret_cast<const float4*>(x)[n];
    v.x *= di; v.y *= di; v.z *= di; v.w *= di;
    reinterpret_cast<float4*>(xp)[n] = v;
}

// L1 gather: SPLIT1 sub-blocks per bucket, LDS tile, coalesced atomic flush
__global__ __launch_bounds__(256) void k_g1(
    const float* __restrict__ xp, const unsigned* __restrict__ pay,
    const int* __restrict__ bcnt, float* __restrict__ agg1) {
    __shared__ float tile[NPB * 4];
    int tid = threadIdx.x;
    for (int i = tid; i < NPB * 4; i += 256) tile[i] = 0.0f;
    __syncthreads();

    int b = blockIdx.x / SPLIT1, s = blockIdx.x % SPLIT1;
    int cnt = bcnt[b]; if (cnt > CAP) cnt = CAP;
    const unsigned* P = pay + (size_t)b * CAP;
    int f = tid & 3, g = tid >> 2;                 // 64 groups; stride 128
#pragma unroll 8
    for (int e = s * 64 + g; e < cnt; e += 64 * SPLIT1) {
        unsigned w = P[e];
        int sn = w & 0x1FFFF, ld = w >> 17;
        atomicAdd(&tile[ld * 4 + f], xp[sn * 4 + f]);
    }
    __syncthreads();

    int lim = N_NODES - b * NPB; if (lim > NPB) lim = NPB;
    lim *= 4;
    for (int idx = tid; idx < lim; idx += 256) {
        float v = tile[idx];
        if (v != 0.0f) atomicAdd(&agg1[(size_t)b * (NPB * 4) + idx], v);
    }
}

// finish L1: a=(agg1+self)*dinv -> relu(@W1+b1) -> @W2 -> *dinv -> t2p
__global__ __launch_bounds__(256) void k_dense1(
    const float* __restrict__ agg1, const float* __restrict__ xp,
    const float* __restrict__ dinv,
    const float* __restrict__ W1, const float* __restrict__ b1,
    const float* __restrict__ W2, float* __restrict__ t2p) {
    __shared__ float sW1[256], sb1[64], sW2[2048];
    int tid = threadIdx.x;
    sW1[tid] = W1[tid];
    if (tid < 64) sb1[tid] = b1[tid];
    for (int i = tid; i < 2048; i += 256) sW2[i] = W2[i];
    __syncthreads();

    int n = blockIdx.x * 256 + tid;
    if (n >= N_NODES) return;
    float di = dinv[n];
    float4 ag = reinterpret_cast<const float4*>(agg1)[n];
    float4 sv = reinterpret_cast<const float4*>(xp)[n];
    float a[4] = {(ag.x + sv.x) * di, (ag.y + sv.y) * di,
                  (ag.z + sv.z) * di, (ag.w + sv.w) * di};
    float t[32];
#pragma unroll
    for (int k = 0; k < 32; ++k) t[k] = 0.0f;
    for (int j = 0; j < 64; ++j) {
        float h = sb1[j];
#pragma unroll
        for (int i = 0; i < 4; ++i) h += a[i] * sW1[i * 64 + j];
        h = fmaxf(h, 0.0f);
#pragma unroll
        for (int k = 0; k < 32; ++k) t[k] += h * sW2[j * 32 + k];
    }
    float4* o = reinterpret_cast<float4*>(t2p + (size_t)n * 32);
#pragma unroll
    for (int q = 0; q < 8; ++q)
        o[q] = make_float4(t[q*4+0]*di, t[q*4+1]*di, t[q*4+2]*di, t[q*4+3]*di);
}

// L2 gather: SPLIT2 sub-blocks per bucket
__global__ __launch_bounds__(256) void k_g2(
    const float* __restrict__ t2p, const unsigned* __restrict__ pay,
    const int* __restrict__ bcnt, float* __restrict__ agg2) {
    __shared__ float tile[NPB * 32];
    int tid = threadIdx.x;
    for (int i = tid; i < NPB * 32; i += 256) tile[i] = 0.0f;
    __syncthreads();

    int b = blockIdx.x / SPLIT2, s = blockIdx.x % SPLIT2;
    int cnt = bcnt[b]; if (cnt > CAP) cnt = CAP;
    const unsigned* P = pay + (size_t)b * CAP;
    int f = tid & 31, g = tid >> 5;                // 8 groups; stride 64
#pragma unroll 8
    for (int e = s * 8 + g; e < cnt; e += 8 * SPLIT2) {
        unsigned w = P[e];
        int sn = w & 0x1FFFF, ld = w >> 17;
        atomicAdd(&tile[ld * 32 + f], t2p[(size_t)sn * 32 + f]);
    }
    __syncthreads();

    int lim = N_NODES - b * NPB; if (lim > NPB) lim = NPB;
    lim *= 32;
    for (int idx = tid; idx < lim; idx += 256) {
        float v = tile[idx];
        if (v != 0.0f) atomicAdd(&agg2[(size_t)b * (NPB * 32) + idx], v);
    }
}

// finish L2: h=relu((agg2+self)*dinv+b2) -> @W3 -> *dinv -> t3p
__global__ __launch_bounds__(256) void k_dense2(
    const float* __restrict__ agg2, const float* __restrict__ t2p,
    const float* __restrict__ dinv,
    const float* __restrict__ b2, const float* __restrict__ W3,
    float* __restrict__ t3p) {
    __shared__ float sb2[32], sW3[512];
    int tid = threadIdx.x;
    if (tid < 32) sb2[tid] = b2[tid];
    for (int i = tid; i < 512; i += 256) sW3[i] = W3[i];
    __syncthreads();

    int n = blockIdx.x * 256 + tid;
    if (n >= N_NODES) return;
    float di = dinv[n];
    const float4* ag = reinterpret_cast<const float4*>(agg2 + (size_t)n * 32);
    const float4* sp = reinterpret_cast<const float4*>(t2p + (size_t)n * 32);
    float h[32];
#pragma unroll
    for (int q = 0; q < 8; ++q) {
        float4 a = ag[q], sv = sp[q];
        h[q*4+0] = fmaxf((a.x + sv.x) * di + sb2[q*4+0], 0.0f);
        h[q*4+1] = fmaxf((a.y + sv.y) * di + sb2[q*4+1], 0.0f);
        h[q*4+2] = fmaxf((a.z + sv.z) * di + sb2[q*4+2], 0.0f);
        h[q*4+3] = fmaxf((a.w + sv.w) * di + sb2[q*4+3], 0.0f);
    }
    float t[16];
#pragma unroll
    for (int k = 0; k < 16; ++k) t[k] = 0.0f;
    for (int j = 0; j < 32; ++j) {
#pragma unroll
        for (int k = 0; k < 16; ++k) t[k] += h[j] * sW3[j * 16 + k];
    }
    float4* o = reinterpret_cast<float4*>(t3p + (size_t)n * 16);
#pragma unroll
    for (int q = 0; q < 4; ++q)
        o[q] = make_float4(t[q*4+0]*di, t[q*4+1]*di, t[q*4+2]*di, t[q*4+3]*di);
}

// L3 gather: SPLIT3 sub-blocks per bucket
__global__ __launch_bounds__(256) void k_g3(
    const float* __restrict__ t3p, const unsigned* __restrict__ pay,
    const int* __restrict__ bcnt, float* __restrict__ agg3) {
    __shared__ float tile[NPB * 16];
    int tid = threadIdx.x;
    for (int i = tid; i < NPB * 16; i += 256) tile[i] = 0.0f;
    __syncthreads();

    int b = blockIdx.x / SPLIT3, s = blockIdx.x % SPLIT3;
    int cnt = bcnt[b]; if (cnt > CAP) cnt = CAP;
    const unsigned* P = pay + (size_t)b * CAP;
    int f = tid & 15, g = tid >> 4;                // 16 groups; stride 128
#pragma unroll 8
    for (int e = s * 16 + g; e < cnt; e += 16 * SPLIT3) {
        unsigned w = P[e];
        int sn = w & 0x1FFFF, ld = w >> 17;
        atomicAdd(&tile[ld * 16 + f], t3p[(size_t)sn * 16 + f]);
    }
    __syncthreads();

    int lim = N_NODES - b * NPB; if (lim > NPB) lim = NPB;
    lim *= 16;
    for (int idx = tid; idx < lim; idx += 256) {
        float v = tile[idx];
        if (v != 0.0f) atomicAdd(&agg3[(size_t)b * (NPB * 16) + idx], v);
    }
}

// finish L3 (+self, +b3), fuse 16->1 head dot and mean-pool segment-sum
__global__ void k_pool(const float* __restrict__ agg3, const float* __restrict__ t3p,
                       const float* __restrict__ dinv,
                       const float* __restrict__ b3, const float* __restrict__ Wl,
                       const int* __restrict__ batch,
                       float* __restrict__ gsum, int* __restrict__ gcnt) {
    int n = blockIdx.x * blockDim.x + threadIdx.x;
    if (n >= N_NODES) return;
    float di = dinv[n];
    const float4* ag = reinterpret_cast<const float4*>(agg3 + (size_t)n * 16);
    const float4* sp = reinterpret_cast<const float4*>(t3p + (size_t)n * 16);
    float s = 0.0f;
#pragma unroll
    for (int q = 0; q < 4; ++q) {
        float4 a = ag[q], sv = sp[q];
        s += ((a.x + sv.x) * di + b3[q*4+0]) * Wl[q*4+0];
        s += ((a.y + sv.y) * di + b3[q*4+1]) * Wl[q*4+1];
        s += ((a.z + sv.z) * di + b3[q*4+2]) * Wl[q*4+2];
        s += ((a.w + sv.w) * di + b3[q*4+3]) * Wl[q*4+3];
    }
    int g = batch[n];
    atomicAdd(&gsum[g], s);
    atomicAdd(&gcnt[g], 1);
}

__global__ void k_head(const float* __restrict__ gsum, const int* __restrict__ gcnt,
                       const float* __restrict__ bl, float* __restrict__ out) {
    int g = blockIdx.x * blockDim.x + threadIdx.x;
    if (g >= N_GRAPHS) return;
    float c = fmaxf((float)gcnt[g], 1.0f);
    out[g] = fmaxf(gsum[g] / c + bl[0], 0.0f);
}

extern "C" void kernel_launch(void* const* d_in, const int* in_sizes, int n_in,
                              void* d_out, int out_size, void* d_ws, size_t ws_size,
                              hipStream_t stream) {
    const float* x  = (const float*)d_in[0];
    const float* W1 = (const float*)d_in[1];
    const float* b1 = (const float*)d_in[2];
    const float* W2 = (const float*)d_in[3];
    const float* b2 = (const float*)d_in[4];
    const float* W3 = (const float*)d_in[5];
    const float* b3 = (const float*)d_in[6];
    const float* Wl = (const float*)d_in[7];
    const float* bl = (const float*)d_in[8];
    const int*   ei = (const int*)d_in[9];        // [2, E] row-major
    const int* batch = (const int*)d_in[10];
    const int* src = ei;
    const int* dst = ei + N_EDGES;
    float* out = (float*)d_out;

    const size_t N = N_NODES, G = N_GRAPHS;
    char* ws = (char*)d_ws;
    int*      deg  = (int*)     (ws);
    float*    dinv = (float*)   (ws + 4 * (N));
    float*    xp   = (float*)   (ws + 4 * (2 * N));
    float*    t2p  = (float*)   (ws + 4 * (6 * N));
    float*    agg3 = (float*)   (ws + 4 * (6 * N));     // aliases t2p (t2p dead)
    float*    t3p  = (float*)   (ws + 4 * (38 * N));
    float*    agg1 = (float*)   (ws + 4 * (38 * N));    // aliases t3p (written later)
    float*    agg2 = (float*)   (ws + 4 * (54 * N));
    int*      bcnt = (int*)     (ws + 4 * (86 * N));
    float*    gsum = (float*)   (ws + 4 * (86 * N + NB));
    int*      gcnt = (int*)     (ws + 4 * (86 * N + NB + G));
    unsigned* pay  = (unsigned*)(ws + 4 * (86 * N + NB + 2 * G));

    const int B = 256;
    const int gN  = (N_NODES + B - 1) / B;           // 391
    const int gB  = (N_EDGES + EPB - 1) / EPB;       // 782
    const int gZ  = (32 * N_NODES + B - 1) / B;      // 12500
    const int gZ3 = (16 * N_NODES + B - 1) / B;      // 6250

    k_zero  <<<gZ, B, 0, stream>>>(deg, bcnt, gsum, gcnt, agg1, agg2);
    k_bucket<<<gB, B, 0, stream>>>(src, dst, deg, bcnt, pay);
    k_prep  <<<gN, B, 0, stream>>>(x, deg, dinv, xp);
    k_g1    <<<NB * SPLIT1, B, 0, stream>>>(xp, pay, bcnt, agg1);
    k_dense1<<<gN, B, 0, stream>>>(agg1, xp, dinv, W1, b1, W2, t2p);
    k_g2    <<<NB * SPLIT2, B, 0, stream>>>(t2p, pay, bcnt, agg2);
    k_dense2<<<gN, B, 0, stream>>>(agg2, t2p, dinv, b2, W3, t3p);
    k_zero3 <<<gZ3, B, 0, stream>>>(agg3);
    k_g3    <<<NB * SPLIT3, B, 0, stream>>>(t3p, pay, bcnt, agg3);
    k_pool  <<<gN, B, 0, stream>>>(agg3, t3p, dinv, b3, Wl, batch, gsum, gcnt);
    k_head  <<<(N_GRAPHS + B - 1) / B, B, 0, stream>>>(gsum, gcnt, bl, out);
}

// Round 8
// 1095.153 us; speedup vs baseline: 1.1193x; 1.1193x over previous
//
#include <hip/hip_runtime.h>

#define N_NODES 100000
#define N_EDGES 3200000
#define N_GRAPHS 1000
#define NB 1024            // dst-range buckets
#define NPB 98             // nodes per bucket
#define CAP 3584           // per-bucket edge capacity (mean 3136 + 8 sigma)
#define EPB 8192           // edges per bucketing block
#define NCH 8              // source chunks (12500 nodes, t2p slice 1.6MB < 4MB L2/XCD)
#define CHN 12500          // nodes per chunk

// ---------------- workspace layout (element offsets, 4B units) --------------
// deg  : int  [N]        @ 0      (written by k_sort histogram)
// dinv : float[N]        @ N
// xp   : float[4N]       @ 2N
// t2p  : float[32N]      @ 6N     [agg3 (16N) aliases @6N after dense2]
// t3p  : float[16N]      @ 38N    [agg1 (4N) aliases @38N before dense2]
// agg2 : float[32N]      @ 54N
// bcnt : int  [NB]       @ 86N
// cnt2 : int  [NB*8]     @ 86N+NB        per-(bucket,chunk) counts
// gsum : float[G]        @ 86N+NB+8192
// gcnt : int  [G]        @ +G
// pay  : uint [NB*CAP]   @ +G            packed (src | local_dst<<17)
// total ≈ 12.29M elem ≈ 49.2 MB (same scale as round-7's proven 49.1 MB)

__global__ void k_zero(int* __restrict__ bcnt, float* __restrict__ gsum,
                       int* __restrict__ gcnt) {
    int i = blockIdx.x * blockDim.x + threadIdx.x;
    if (i < NB) bcnt[i] = 0;
    if (i < N_GRAPHS) { gsum[i] = 0.0f; gcnt[i] = 0; }
}

// two-level bucketize by dst: LDS histogram -> scan -> LDS place -> run flush
__global__ __launch_bounds__(256) void k_bucket(
    const int* __restrict__ src, const int* __restrict__ dst,
    int* __restrict__ bcnt, unsigned* __restrict__ pay) {
    __shared__ int cnt[NB];
    __shared__ int off[NB];
    __shared__ int scanbuf[256];
    __shared__ unsigned rec[EPB];

    int tid = threadIdx.x;
    int e0 = blockIdx.x * EPB;
    for (int i = tid; i < NB; i += 256) cnt[i] = 0;
    __syncthreads();

#pragma unroll
    for (int k = 0; k < EPB / 256; ++k) {
        int e = e0 + k * 256 + tid;
        if (e < N_EDGES) atomicAdd(&cnt[(unsigned)dst[e] / NPB], 1);
    }
    __syncthreads();

    int base = tid * 4;
    int c0 = cnt[base], c1 = cnt[base + 1], c2 = cnt[base + 2], c3 = cnt[base + 3];
    int part = c0 + c1 + c2 + c3;
    scanbuf[tid] = part;
    __syncthreads();
    for (int o = 1; o < 256; o <<= 1) {
        int v = (tid >= o) ? scanbuf[tid - o] : 0;
        __syncthreads();
        scanbuf[tid] += v;
        __syncthreads();
    }
    int ex = scanbuf[tid] - part;
    off[base]     = ex;
    off[base + 1] = ex + c0;
    off[base + 2] = ex + c0 + c1;
    off[base + 3] = ex + c0 + c1 + c2;
    __syncthreads();

#pragma unroll
    for (int k = 0; k < EPB / 256; ++k) {
        int e = e0 + k * 256 + tid;
        if (e < N_EDGES) {
            unsigned s = (unsigned)src[e];
            unsigned d = (unsigned)dst[e];
            unsigned b = d / NPB;
            unsigned ld = d - b * NPB;
            int p = atomicAdd(&off[b], 1);
            rec[p] = s | (ld << 17);
        }
    }
    __syncthreads();

    for (int b = tid; b < NB; b += 256) {
        int c = cnt[b];
        if (c == 0) continue;
        int ls = off[b] - c;
        int gb = atomicAdd(&bcnt[b], c);
        unsigned* dstp = pay + (size_t)b * CAP;
        for (int k = 0; k < c; ++k) {
            int gp = gb + k;
            if (gp < CAP) dstp[gp] = rec[ls + k];
        }
    }
}

// per-bucket: sort records by src chunk (counting sort in LDS), write cnt2,
// and produce deg[] via local-dst histogram (no global atomics).
__global__ __launch_bounds__(256) void k_sort(
    unsigned* __restrict__ pay, const int* __restrict__ bcnt,
    int* __restrict__ cnt2, int* __restrict__ deg) {
    __shared__ unsigned rec[CAP], rec2[CAP];
    __shared__ int hc[NCH], off8[NCH], hl[NPB];
    int tid = threadIdx.x;
    int b = blockIdx.x;
    int cnt = bcnt[b]; if (cnt > CAP) cnt = CAP;
    unsigned* P = pay + (size_t)b * CAP;

    if (tid < NCH) hc[tid] = 0;
    if (tid < NPB) hl[tid] = 0;
    __syncthreads();

    for (int i = tid; i < cnt; i += 256) {
        unsigned w = P[i];
        rec[i] = w;
        atomicAdd(&hc[(w & 0x1FFFF) / CHN], 1);
        atomicAdd(&hl[w >> 17], 1);
    }
    __syncthreads();

    if (tid == 0) {
        int run = 0;
#pragma unroll
        for (int c = 0; c < NCH; ++c) { off8[c] = run; run += hc[c]; }
    }
    if (tid < NCH) cnt2[b * NCH + tid] = hc[tid];
    __syncthreads();

    for (int i = tid; i < cnt; i += 256) {
        unsigned w = rec[i];
        int p = atomicAdd(&off8[(w & 0x1FFFF) / CHN], 1);
        rec2[p] = w;
    }
    __syncthreads();

    for (int i = tid; i < cnt; i += 256) P[i] = rec2[i];
    if (tid < NPB) {
        int n = b * NPB + tid;
        if (n < N_NODES) deg[n] = hl[tid];
    }
}

__global__ void k_prep(const float* __restrict__ x, const int* __restrict__ deg,
                       float* __restrict__ dinv, float* __restrict__ xp) {
    int n = blockIdx.x * blockDim.x + threadIdx.x;
    if (n >= N_NODES) return;
    float di = rsqrtf((float)(deg[n] + 1));
    dinv[n] = di;
    float4 v = reinterpret_cast<const float4*>(x)[n];
    v.x *= di; v.y *= di; v.z *= di; v.w *= di;
    reinterpret_cast<float4*>(xp)[n] = v;
}

// L1 gather: xp is 1.6MB total (L2-resident everywhere); plain-store flush
__global__ __launch_bounds__(256) void k_g1(
    const float* __restrict__ xp, const unsigned* __restrict__ pay,
    const int* __restrict__ bcnt, float* __restrict__ agg1) {
    __shared__ float tile[NPB * 4];
    int tid = threadIdx.x;
    for (int i = tid; i < NPB * 4; i += 256) tile[i] = 0.0f;
    __syncthreads();

    int b = blockIdx.x;
    int cnt = bcnt[b]; if (cnt > CAP) cnt = CAP;
    const unsigned* P = pay + (size_t)b * CAP;
    int f = tid & 3, g = tid >> 2;
#pragma unroll 4
    for (int e = g; e < cnt; e += 64) {
        unsigned w = P[e];
        int sn = w & 0x1FFFF, ld = w >> 17;
        atomicAdd(&tile[ld * 4 + f], xp[sn * 4 + f]);
    }
    __syncthreads();

    int lim = N_NODES - b * NPB; if (lim > NPB) lim = NPB;
    lim *= 4;
    for (int idx = tid; idx < lim; idx += 256)
        agg1[(size_t)b * (NPB * 4) + idx] = tile[idx];
}

// finish L1: a=(agg1+self)*dinv -> relu(@W1+b1) -> @W2 -> *dinv -> t2p
__global__ __launch_bounds__(256) void k_dense1(
    const float* __restrict__ agg1, const float* __restrict__ xp,
    const float* __restrict__ dinv,
    const float* __restrict__ W1, const float* __restrict__ b1,
    const float* __restrict__ W2, float* __restrict__ t2p) {
    __shared__ float sW1[256], sb1[64], sW2[2048];
    int tid = threadIdx.x;
    sW1[tid] = W1[tid];
    if (tid < 64) sb1[tid] = b1[tid];
    for (int i = tid; i < 2048; i += 256) sW2[i] = W2[i];
    __syncthreads();

    int n = blockIdx.x * 256 + tid;
    if (n >= N_NODES) return;
    float di = dinv[n];
    float4 ag = reinterpret_cast<const float4*>(agg1)[n];
    float4 sv = reinterpret_cast<const float4*>(xp)[n];
    float a[4] = {(ag.x + sv.x) * di, (ag.y + sv.y) * di,
                  (ag.z + sv.z) * di, (ag.w + sv.w) * di};
    float t[32];
#pragma unroll
    for (int k = 0; k < 32; ++k) t[k] = 0.0f;
    for (int j = 0; j < 64; ++j) {
        float h = sb1[j];
#pragma unroll
        for (int i = 0; i < 4; ++i) h += a[i] * sW1[i * 64 + j];
        h = fmaxf(h, 0.0f);
#pragma unroll
        for (int k = 0; k < 32; ++k) t[k] += h * sW2[j * 32 + k];
    }
    float4* o = reinterpret_cast<float4*>(t2p + (size_t)n * 32);
#pragma unroll
    for (int q = 0; q < 8; ++q)
        o[q] = make_float4(t[q*4+0]*di, t[q*4+1]*di, t[q*4+2]*di, t[q*4+3]*di);
}

// L2 gather: chunk-phased (all 1024 blocks resident; each chunk's t2p slice
// = 1.6MB, L2-resident in every XCD during its phase); plain-store flush
__global__ __launch_bounds__(256) void k_g2(
    const float* __restrict__ t2p, const unsigned* __restrict__ pay,
    const int* __restrict__ cnt2, float* __restrict__ agg2) {
    __shared__ float tile[NPB * 32];
    int tid = threadIdx.x;
    for (int i = tid; i < NPB * 32; i += 256) tile[i] = 0.0f;
    __syncthreads();

    int b = blockIdx.x;
    const unsigned* P = pay + (size_t)b * CAP;
    int f = tid & 31, g = tid >> 5;
    int off = 0;
    for (int c = 0; c < NCH; ++c) {
        int sc = cnt2[b * NCH + c];
        int end = off + sc;
#pragma unroll 4
        for (int e = off + g; e < end; e += 8) {
            unsigned w = P[e];
            int sn = w & 0x1FFFF, ld = w >> 17;
            atomicAdd(&tile[ld * 32 + f], t2p[(size_t)sn * 32 + f]);
        }
        off = end;
        __syncthreads();           // keep block's waves phase-aligned per chunk
    }

    int lim = N_NODES - b * NPB; if (lim > NPB) lim = NPB;
    lim *= 32;
    for (int idx = tid; idx < lim; idx += 256)
        agg2[(size_t)b * (NPB * 32) + idx] = tile[idx];
}

// finish L2: h=relu((agg2+self)*dinv+b2) -> @W3 -> *dinv -> t3p
__global__ __launch_bounds__(256) void k_dense2(
    const float* __restrict__ agg2, const float* __restrict__ t2p,
    const float* __restrict__ dinv,
    const float* __restrict__ b2, const float* __restrict__ W3,
    float* __restrict__ t3p) {
    __shared__ float sb2[32], sW3[512];
    int tid = threadIdx.x;
    if (tid < 32) sb2[tid] = b2[tid];
    for (int i = tid; i < 512; i += 256) sW3[i] = W3[i];
    __syncthreads();

    int n = blockIdx.x * 256 + tid;
    if (n >= N_NODES) return;
    float di = dinv[n];
    const float4* ag = reinterpret_cast<const float4*>(agg2 + (size_t)n * 32);
    const float4* sp = reinterpret_cast<const float4*>(t2p + (size_t)n * 32);
    float h[32];
#pragma unroll
    for (int q = 0; q < 8; ++q) {
        float4 a = ag[q], sv = sp[q];
        h[q*4+0] = fmaxf((a.x + sv.x) * di + sb2[q*4+0], 0.0f);
        h[q*4+1] = fmaxf((a.y + sv.y) * di + sb2[q*4+1], 0.0f);
        h[q*4+2] = fmaxf((a.z + sv.z) * di + sb2[q*4+2], 0.0f);
        h[q*4+3] = fmaxf((a.w + sv.w) * di + sb2[q*4+3], 0.0f);
    }
    float t[16];
#pragma unroll
    for (int k = 0; k < 16; ++k) t[k] = 0.0f;
    for (int j = 0; j < 32; ++j) {
#pragma unroll
        for (int k = 0; k < 16; ++k) t[k] += h[j] * sW3[j * 16 + k];
    }
    float4* o = reinterpret_cast<float4*>(t3p + (size_t)n * 16);
#pragma unroll
    for (int q = 0; q < 4; ++q)
        o[q] = make_float4(t[q*4+0]*di, t[q*4+1]*di, t[q*4+2]*di, t[q*4+3]*di);
}

// L3 gather: chunk-phased like k_g2 (t3p slice = 0.8MB/chunk)
__global__ __launch_bounds__(256) void k_g3(
    const float* __restrict__ t3p, const unsigned* __restrict__ pay,
    const int* __restrict__ cnt2, float* __restrict__ agg3) {
    __shared__ float tile[NPB * 16];
    int tid = threadIdx.x;
    for (int i = tid; i < NPB * 16; i += 256) tile[i] = 0.0f;
    __syncthreads();

    int b = blockIdx.x;
    const unsigned* P = pay + (size_t)b * CAP;
    int f = tid & 15, g = tid >> 4;
    int off = 0;
    for (int c = 0; c < NCH; ++c) {
        int sc = cnt2[b * NCH + c];
        int end = off + sc;
#pragma unroll 4
        for (int e = off + g; e < end; e += 16) {
            unsigned w = P[e];
            int sn = w & 0x1FFFF, ld = w >> 17;
            atomicAdd(&tile[ld * 16 + f], t3p[(size_t)sn * 16 + f]);
        }
        off = end;
        __syncthreads();
    }

    int lim = N_NODES - b * NPB; if (lim > NPB) lim = NPB;
    lim *= 16;
    for (int idx = tid; idx < lim; idx += 256)
        agg3[(size_t)b * (NPB * 16) + idx] = tile[idx];
}

// finish L3 (+self, +b3), fuse 16->1 head dot and mean-pool segment-sum
__global__ void k_pool(const float* __restrict__ agg3, const float* __restrict__ t3p,
                       const float* __restrict__ dinv,
                       const float* __restrict__ b3, const float* __restrict__ Wl,
                       const int* __restrict__ batch,
                       float* __restrict__ gsum, int* __restrict__ gcnt) {
    int n = blockIdx.x * blockDim.x + threadIdx.x;
    if (n >= N_NODES) return;
    float di = dinv[n];
    const float4* ag = reinterpret_cast<const float4*>(agg3 + (size_t)n * 16);
    const float4* sp = reinterpret_cast<const float4*>(t3p + (size_t)n * 16);
    float s = 0.0f;
#pragma unroll
    for (int q = 0; q < 4; ++q) {
        float4 a = ag[q], sv = sp[q];
        s += ((a.x + sv.x) * di + b3[q*4+0]) * Wl[q*4+0];
        s += ((a.y + sv.y) * di + b3[q*4+1]) * Wl[q*4+1];
        s += ((a.z + sv.z) * di + b3[q*4+2]) * Wl[q*4+2];
        s += ((a.w + sv.w) * di + b3[q*4+3]) * Wl[q*4+3];
    }
    int g = batch[n];
    atomicAdd(&gsum[g], s);
    atomicAdd(&gcnt[g], 1);
}

__global__ void k_head(const float* __restrict__ gsum, const int* __restrict__ gcnt,
                       const float* __restrict__ bl, float* __restrict__ out) {
    int g = blockIdx.x * blockDim.x + threadIdx.x;
    if (g >= N_GRAPHS) return;
    float c = fmaxf((float)gcnt[g], 1.0f);
    out[g] = fmaxf(gsum[g] / c + bl[0], 0.0f);
}

extern "C" void kernel_launch(void* const* d_in, const int* in_sizes, int n_in,
                              void* d_out, int out_size, void* d_ws, size_t ws_size,
                              hipStream_t stream) {
    const float* x  = (const float*)d_in[0];
    const float* W1 = (const float*)d_in[1];
    const float* b1 = (const float*)d_in[2];
    const float* W2 = (const float*)d_in[3];
    const float* b2 = (const float*)d_in[4];
    const float* W3 = (const float*)d_in[5];
    const float* b3 = (const float*)d_in[6];
    const float* Wl = (const float*)d_in[7];
    const float* bl = (const float*)d_in[8];
    const int*   ei = (const int*)d_in[9];        // [2, E] row-major
    const int* batch = (const int*)d_in[10];
    const int* src = ei;
    const int* dst = ei + N_EDGES;
    float* out = (float*)d_out;

    const size_t N = N_NODES, G = N_GRAPHS;
    char* ws = (char*)d_ws;
    int*      deg  = (int*)     (ws);
    float*    dinv = (float*)   (ws + 4 * (N));
    float*    xp   = (float*)   (ws + 4 * (2 * N));
    float*    t2p  = (float*)   (ws + 4 * (6 * N));
    float*    agg3 = (float*)   (ws + 4 * (6 * N));     // aliases t2p (dead then)
    float*    t3p  = (float*)   (ws + 4 * (38 * N));
    float*    agg1 = (float*)   (ws + 4 * (38 * N));    // aliases t3p (written later)
    float*    agg2 = (float*)   (ws + 4 * (54 * N));
    int*      bcnt = (int*)     (ws + 4 * (86 * N));
    int*      cnt2 = (int*)     (ws + 4 * (86 * N + NB));
    float*    gsum = (float*)   (ws + 4 * (86 * N + NB + NB * NCH));
    int*      gcnt = (int*)     (ws + 4 * (86 * N + NB + NB * NCH + G));
    unsigned* pay  = (unsigned*)(ws + 4 * (86 * N + NB + NB * NCH + 2 * G));

    const int B = 256;
    const int gN = (N_NODES + B - 1) / B;            // 391
    const int gB = (N_EDGES + EPB - 1) / EPB;        // 391

    k_zero  <<<gN, B, 0, stream>>>(bcnt, gsum, gcnt);
    k_bucket<<<gB, B, 0, stream>>>(src, dst, bcnt, pay);
    k_sort  <<<NB, B, 0, stream>>>(pay, bcnt, cnt2, deg);
    k_prep  <<<gN, B, 0, stream>>>(x, deg, dinv, xp);
    k_g1    <<<NB, B, 0, stream>>>(xp, pay, bcnt, agg1);
    k_dense1<<<gN, B, 0, stream>>>(agg1, xp, dinv, W1, b1, W2, t2p);
    k_g2    <<<NB, B, 0, stream>>>(t2p, pay, cnt2, agg2);
    k_dense2<<<gN, B, 0, stream>>>(agg2, t2p, dinv, b2, W3, t3p);
    k_g3    <<<NB, B, 0, stream>>>(t3p, pay, cnt2, agg3);
    k_pool  <<<gN, B, 0, stream>>>(agg3, t3p, dinv, b3, Wl, batch, gsum, gcnt);
    k_head  <<<(N_GRAPHS + B - 1) / B, B, 0, stream>>>(gsum, gcnt, bl, out);
}

// Round 9
// 1085.435 us; speedup vs baseline: 1.1293x; 1.0090x over previous
//
#include <hip/hip_runtime.h>
#include <hip/hip_fp16.h>

#define N_NODES 100000
#define N_EDGES 3200000
#define N_GRAPHS 1000
#define NB 1024            // dst-range buckets
#define NPB 98             // nodes per bucket
#define CAP 3584           // per-bucket edge capacity (mean 3136 + 8 sigma)
#define EPB 8192           // edges per bucketing block
#define NCH 8              // source chunks
#define CHN 12500          // nodes per chunk

// ---------------- workspace layout (element offsets, 4B units) --------------
// dinv : float[N]        @ 0
// xp   : float[4N]       @ N
// t2ph : half [32N]      @ 5N    (16N units)  (h1@W2)*dinv, fp16
// t3ph : half [16N]      @ 21N   (8N units)   (h2@W3)*dinv, fp16
// agg1 : float[4N]       @ 29N
// agg2 : float[32N]      @ 33N
// agg3 : float[16N]      @ 65N
// bcnt : int  [NB]       @ 81N
// cnt2 : int  [NB*NCH]   @ 81N+NB
// gsum : float[G]        @ +NB*NCH
// gcnt : int  [G]        @ +G
// pay  : uint [NB*CAP]   @ +G
// total ≈ 11.78M units ≈ 47.1 MB

__global__ void k_zero(int* __restrict__ bcnt, float* __restrict__ gsum,
                       int* __restrict__ gcnt) {
    int i = blockIdx.x * blockDim.x + threadIdx.x;
    if (i < NB) bcnt[i] = 0;
    if (i < N_GRAPHS) { gsum[i] = 0.0f; gcnt[i] = 0; }
}

// two-level bucketize by dst: LDS histogram -> scan -> LDS place -> run flush
__global__ __launch_bounds__(256) void k_bucket(
    const int* __restrict__ src, const int* __restrict__ dst,
    int* __restrict__ bcnt, unsigned* __restrict__ pay) {
    __shared__ int cnt[NB];
    __shared__ int off[NB];
    __shared__ int scanbuf[256];
    __shared__ unsigned rec[EPB];

    int tid = threadIdx.x;
    int e0 = blockIdx.x * EPB;
    for (int i = tid; i < NB; i += 256) cnt[i] = 0;
    __syncthreads();

#pragma unroll
    for (int k = 0; k < EPB / 256; ++k) {
        int e = e0 + k * 256 + tid;
        if (e < N_EDGES) atomicAdd(&cnt[(unsigned)dst[e] / NPB], 1);
    }
    __syncthreads();

    int base = tid * 4;
    int c0 = cnt[base], c1 = cnt[base + 1], c2 = cnt[base + 2], c3 = cnt[base + 3];
    int part = c0 + c1 + c2 + c3;
    scanbuf[tid] = part;
    __syncthreads();
    for (int o = 1; o < 256; o <<= 1) {
        int v = (tid >= o) ? scanbuf[tid - o] : 0;
        __syncthreads();
        scanbuf[tid] += v;
        __syncthreads();
    }
    int ex = scanbuf[tid] - part;
    off[base]     = ex;
    off[base + 1] = ex + c0;
    off[base + 2] = ex + c0 + c1;
    off[base + 3] = ex + c0 + c1 + c2;
    __syncthreads();

#pragma unroll
    for (int k = 0; k < EPB / 256; ++k) {
        int e = e0 + k * 256 + tid;
        if (e < N_EDGES) {
            unsigned s = (unsigned)src[e];
            unsigned d = (unsigned)dst[e];
            unsigned b = d / NPB;
            unsigned ld = d - b * NPB;
            int p = atomicAdd(&off[b], 1);
            rec[p] = s | (ld << 17);
        }
    }
    __syncthreads();

    for (int b = tid; b < NB; b += 256) {
        int c = cnt[b];
        if (c == 0) continue;
        int ls = off[b] - c;
        int gb = atomicAdd(&bcnt[b], c);
        unsigned* dstp = pay + (size_t)b * CAP;
        for (int k = 0; k < c; ++k) {
            int gp = gb + k;
            if (gp < CAP) dstp[gp] = rec[ls + k];
        }
    }
}

// per-bucket: counting-sort records by src chunk; write cnt2; local-dst degree
// histogram -> dinv + xp for this bucket's own nodes (k_prep merged in).
__global__ __launch_bounds__(256) void k_sort(
    unsigned* __restrict__ pay, const int* __restrict__ bcnt,
    int* __restrict__ cnt2, const float* __restrict__ x,
    float* __restrict__ dinv, float* __restrict__ xp) {
    __shared__ unsigned rec[CAP], rec2[CAP];
    __shared__ int hc[NCH], off8[NCH], hl[NPB];
    int tid = threadIdx.x;
    int b = blockIdx.x;
    int cnt = bcnt[b]; if (cnt > CAP) cnt = CAP;
    unsigned* P = pay + (size_t)b * CAP;

    if (tid < NCH) hc[tid] = 0;
    if (tid < NPB) hl[tid] = 0;
    __syncthreads();

    for (int i = tid; i < cnt; i += 256) {
        unsigned w = P[i];
        rec[i] = w;
        atomicAdd(&hc[(w & 0x1FFFF) / CHN], 1);
        atomicAdd(&hl[w >> 17], 1);
    }
    __syncthreads();

    // fused k_prep: this bucket's nodes get dinv + pre-scaled features
    if (tid < NPB) {
        int n = b * NPB + tid;
        if (n < N_NODES) {
            float di = rsqrtf((float)(hl[tid] + 1));   // +1 self-loop
            dinv[n] = di;
            float4 v = reinterpret_cast<const float4*>(x)[n];
            v.x *= di; v.y *= di; v.z *= di; v.w *= di;
            reinterpret_cast<float4*>(xp)[n] = v;
        }
    }

    if (tid == 0) {
        int run = 0;
#pragma unroll
        for (int c = 0; c < NCH; ++c) { off8[c] = run; run += hc[c]; }
    }
    if (tid < NCH) cnt2[b * NCH + tid] = hc[tid];
    __syncthreads();

    for (int i = tid; i < cnt; i += 256) {
        unsigned w = rec[i];
        int p = atomicAdd(&off8[(w & 0x1FFFF) / CHN], 1);
        rec2[p] = w;
    }
    __syncthreads();

    for (int i = tid; i < cnt; i += 256) P[i] = rec2[i];
}

// L1 gather: xp fp32 (1.6MB table); plain-store flush
__global__ __launch_bounds__(256) void k_g1(
    const float* __restrict__ xp, const unsigned* __restrict__ pay,
    const int* __restrict__ bcnt, float* __restrict__ agg1) {
    __shared__ float tile[NPB * 4];
    int tid = threadIdx.x;
    for (int i = tid; i < NPB * 4; i += 256) tile[i] = 0.0f;
    __syncthreads();

    int b = blockIdx.x;
    int cnt = bcnt[b]; if (cnt > CAP) cnt = CAP;
    const unsigned* P = pay + (size_t)b * CAP;
    int f = tid & 3, g = tid >> 2;
#pragma unroll 4
    for (int e = g; e < cnt; e += 64) {
        unsigned w = P[e];
        int sn = w & 0x1FFFF, ld = w >> 17;
        atomicAdd(&tile[ld * 4 + f], xp[sn * 4 + f]);
    }
    __syncthreads();

    int lim = N_NODES - b * NPB; if (lim > NPB) lim = NPB;
    lim *= 4;
    for (int idx = tid; idx < lim; idx += 256)
        agg1[(size_t)b * (NPB * 4) + idx] = tile[idx];
}

// finish L1: a=(agg1+self)*dinv -> relu(@W1+b1) -> @W2 -> *dinv -> t2ph (fp16)
__global__ __launch_bounds__(256) void k_dense1(
    const float* __restrict__ agg1, const float* __restrict__ xp,
    const float* __restrict__ dinv,
    const float* __restrict__ W1, const float* __restrict__ b1,
    const float* __restrict__ W2, __half* __restrict__ t2ph) {
    __shared__ float sW1[256], sb1[64], sW2[2048];
    int tid = threadIdx.x;
    sW1[tid] = W1[tid];
    if (tid < 64) sb1[tid] = b1[tid];
    for (int i = tid; i < 2048; i += 256) sW2[i] = W2[i];
    __syncthreads();

    int n = blockIdx.x * 256 + tid;
    if (n >= N_NODES) return;
    float di = dinv[n];
    float4 ag = reinterpret_cast<const float4*>(agg1)[n];
    float4 sv = reinterpret_cast<const float4*>(xp)[n];
    float a[4] = {(ag.x + sv.x) * di, (ag.y + sv.y) * di,
                  (ag.z + sv.z) * di, (ag.w + sv.w) * di};
    float t[32];
#pragma unroll
    for (int k = 0; k < 32; ++k) t[k] = 0.0f;
    for (int j = 0; j < 64; ++j) {
        float h = sb1[j];
#pragma unroll
        for (int i = 0; i < 4; ++i) h += a[i] * sW1[i * 64 + j];
        h = fmaxf(h, 0.0f);
#pragma unroll
        for (int k = 0; k < 32; ++k) t[k] += h * sW2[j * 32 + k];
    }
    __half2* o = reinterpret_cast<__half2*>(t2ph + (size_t)n * 32);
#pragma unroll
    for (int q = 0; q < 16; ++q)
        o[q] = __floats2half2_rn(t[2*q] * di, t[2*q+1] * di);
}

// L2 gather: fp16 features, 64B/edge segments (2B/lane x 32 lanes)
__global__ __launch_bounds__(256) void k_g2(
    const __half* __restrict__ t2ph, const unsigned* __restrict__ pay,
    const int* __restrict__ cnt2, float* __restrict__ agg2) {
    __shared__ float tile[NPB * 32];
    int tid = threadIdx.x;
    for (int i = tid; i < NPB * 32; i += 256) tile[i] = 0.0f;
    __syncthreads();

    int b = blockIdx.x;
    const unsigned* P = pay + (size_t)b * CAP;
    int f = tid & 31, g = tid >> 5;
    int off = 0;
    for (int c = 0; c < NCH; ++c) {
        int sc = cnt2[b * NCH + c];
        int end = off + sc;
#pragma unroll 4
        for (int e = off + g; e < end; e += 8) {
            unsigned w = P[e];
            int sn = w & 0x1FFFF, ld = w >> 17;
            float v = __half2float(t2ph[(size_t)sn * 32 + f]);
            atomicAdd(&tile[ld * 32 + f], v);
        }
        off = end;
        __syncthreads();
    }

    int lim = N_NODES - b * NPB; if (lim > NPB) lim = NPB;
    lim *= 32;
    for (int idx = tid; idx < lim; idx += 256)
        agg2[(size_t)b * (NPB * 32) + idx] = tile[idx];
}

// finish L2: h=relu((agg2+self)*dinv+b2) -> @W3 -> *dinv -> t3ph (fp16)
__global__ __launch_bounds__(256) void k_dense2(
    const float* __restrict__ agg2, const __half* __restrict__ t2ph,
    const float* __restrict__ dinv,
    const float* __restrict__ b2, const float* __restrict__ W3,
    __half* __restrict__ t3ph) {
    __shared__ float sb2[32], sW3[512];
    int tid = threadIdx.x;
    if (tid < 32) sb2[tid] = b2[tid];
    for (int i = tid; i < 512; i += 256) sW3[i] = W3[i];
    __syncthreads();

    int n = blockIdx.x * 256 + tid;
    if (n >= N_NODES) return;
    float di = dinv[n];
    const float2* ag = reinterpret_cast<const float2*>(agg2 + (size_t)n * 32);
    const __half2* sp = reinterpret_cast<const __half2*>(t2ph + (size_t)n * 32);
    float h[32];
#pragma unroll
    for (int q = 0; q < 16; ++q) {
        float2 a = ag[q];
        float2 sv = __half22float2(sp[q]);
        h[2*q]   = fmaxf((a.x + sv.x) * di + sb2[2*q],   0.0f);
        h[2*q+1] = fmaxf((a.y + sv.y) * di + sb2[2*q+1], 0.0f);
    }
    float t[16];
#pragma unroll
    for (int k = 0; k < 16; ++k) t[k] = 0.0f;
    for (int j = 0; j < 32; ++j) {
#pragma unroll
        for (int k = 0; k < 16; ++k) t[k] += h[j] * sW3[j * 16 + k];
    }
    __half2* o = reinterpret_cast<__half2*>(t3ph + (size_t)n * 16);
#pragma unroll
    for (int q = 0; q < 8; ++q)
        o[q] = __floats2half2_rn(t[2*q] * di, t[2*q+1] * di);
}

// L3 gather: fp16 features, 32B/edge segments (2B/lane x 16 lanes)
__global__ __launch_bounds__(256) void k_g3(
    const __half* __restrict__ t3ph, const unsigned* __restrict__ pay,
    const int* __restrict__ cnt2, float* __restrict__ agg3) {
    __shared__ float tile[NPB * 16];
    int tid = threadIdx.x;
    for (int i = tid; i < NPB * 16; i += 256) tile[i] = 0.0f;
    __syncthreads();

    int b = blockIdx.x;
    const unsigned* P = pay + (size_t)b * CAP;
    int f = tid & 15, g = tid >> 4;
    int off = 0;
    for (int c = 0; c < NCH; ++c) {
        int sc = cnt2[b * NCH + c];
        int end = off + sc;
#pragma unroll 4
        for (int e = off + g; e < end; e += 16) {
            unsigned w = P[e];
            int sn = w & 0x1FFFF, ld = w >> 17;
            float v = __half2float(t3ph[(size_t)sn * 16 + f]);
            atomicAdd(&tile[ld * 16 + f], v);
        }
        off = end;
        __syncthreads();
    }

    int lim = N_NODES - b * NPB; if (lim > NPB) lim = NPB;
    lim *= 16;
    for (int idx = tid; idx < lim; idx += 256)
        agg3[(size_t)b * (NPB * 16) + idx] = tile[idx];
}

// finish L3 (+self, +b3), fuse 16->1 head dot and mean-pool segment-sum
__global__ void k_pool(const float* __restrict__ agg3, const __half* __restrict__ t3ph,
                       const float* __restrict__ dinv,
                       const float* __restrict__ b3, const float* __restrict__ Wl,
                       const int* __restrict__ batch,
                       float* __restrict__ gsum, int* __restrict__ gcnt) {
    int n = blockIdx.x * blockDim.x + threadIdx.x;
    if (n >= N_NODES) return;
    float di = dinv[n];
    const float2* ag = reinterpret_cast<const float2*>(agg3 + (size_t)n * 16);
    const __half2* sp = reinterpret_cast<const __half2*>(t3ph + (size_t)n * 16);
    float s = 0.0f;
#pragma unroll
    for (int q = 0; q < 8; ++q) {
        float2 a = ag[q];
        float2 sv = __half22float2(sp[q]);
        s += ((a.x + sv.x) * di + b3[2*q])   * Wl[2*q];
        s += ((a.y + sv.y) * di + b3[2*q+1]) * Wl[2*q+1];
    }
    int g = batch[n];
    atomicAdd(&gsum[g], s);
    atomicAdd(&gcnt[g], 1);
}

__global__ void k_head(const float* __restrict__ gsum, const int* __restrict__ gcnt,
                       const float* __restrict__ bl, float* __restrict__ out) {
    int g = blockIdx.x * blockDim.x + threadIdx.x;
    if (g >= N_GRAPHS) return;
    float c = fmaxf((float)gcnt[g], 1.0f);
    out[g] = fmaxf(gsum[g] / c + bl[0], 0.0f);
}

extern "C" void kernel_launch(void* const* d_in, const int* in_sizes, int n_in,
                              void* d_out, int out_size, void* d_ws, size_t ws_size,
                              hipStream_t stream) {
    const float* x  = (const float*)d_in[0];
    const float* W1 = (const float*)d_in[1];
    const float* b1 = (const float*)d_in[2];
    const float* W2 = (const float*)d_in[3];
    const float* b2 = (const float*)d_in[4];
    const float* W3 = (const float*)d_in[5];
    const float* b3 = (const float*)d_in[6];
    const float* Wl = (const float*)d_in[7];
    const float* bl = (const float*)d_in[8];
    const int*   ei = (const int*)d_in[9];        // [2, E] row-major
    const int* batch = (const int*)d_in[10];
    const int* src = ei;
    const int* dst = ei + N_EDGES;
    float* out = (float*)d_out;

    const size_t N = N_NODES, G = N_GRAPHS;
    char* ws = (char*)d_ws;
    float*    dinv = (float*)   (ws);
    float*    xp   = (float*)   (ws + 4 * (N));
    __half*   t2ph = (__half*)  (ws + 4 * (5 * N));
    __half*   t3ph = (__half*)  (ws + 4 * (21 * N));
    float*    agg1 = (float*)   (ws + 4 * (29 * N));
    float*    agg2 = (float*)   (ws + 4 * (33 * N));
    float*    agg3 = (float*)   (ws + 4 * (65 * N));
    int*      bcnt = (int*)     (ws + 4 * (81 * N));
    int*      cnt2 = (int*)     (ws + 4 * (81 * N + NB));
    float*    gsum = (float*)   (ws + 4 * (81 * N + NB + NB * NCH));
    int*      gcnt = (int*)     (ws + 4 * (81 * N + NB + NB * NCH + G));
    unsigned* pay  = (unsigned*)(ws + 4 * (81 * N + NB + NB * NCH + 2 * G));

    const int B = 256;
    const int gN = (N_NODES + B - 1) / B;            // 391
    const int gB = (N_EDGES + EPB - 1) / EPB;        // 391

    k_zero  <<<gN, B, 0, stream>>>(bcnt, gsum, gcnt);
    k_bucket<<<gB, B, 0, stream>>>(src, dst, bcnt, pay);
    k_sort  <<<NB, B, 0, stream>>>(pay, bcnt, cnt2, x, dinv, xp);
    k_g1    <<<NB, B, 0, stream>>>(xp, pay, bcnt, agg1);
    k_dense1<<<gN, B, 0, stream>>>(agg1, xp, dinv, W1, b1, W2, t2ph);
    k_g2    <<<NB, B, 0, stream>>>(t2ph, pay, cnt2, agg2);
    k_dense2<<<gN, B, 0, stream>>>(agg2, t2ph, dinv, b2, W3, t3ph);
    k_g3    <<<NB, B, 0, stream>>>(t3ph, pay, cnt2, agg3);
    k_pool  <<<gN, B, 0, stream>>>(agg3, t3ph, dinv, b3, Wl, batch, gsum, gcnt);
    k_head  <<<(N_GRAPHS + B - 1) / B, B, 0, stream>>>(gsum, gcnt, bl, out);
}

// Round 11
// 328.447 us; speedup vs baseline: 3.7320x; 3.3048x over previous
//
#include <hip/hip_runtime.h>
#include <hip/hip_fp16.h>

#define N_NODES 100000
#define N_EDGES 3200000
#define N_GRAPHS 1000
#define NB 1024            // dst-range buckets
#define NPB 98             // nodes per bucket
#define CAP 3584           // per-bucket edge capacity (mean 3136 + 8 sigma)
#define EPB 8192           // edges per bucketing block

// ---------------- workspace layout (element offsets, 4B units) --------------
// dinv : float[N]        @ 0
// xp   : float[4N]       @ N
// t2ph : half [32N]      @ 5N    (16N units)
// t3ph : half [16N]      @ 21N   (8N units)
// agg1 : float[4N]       @ 29N
// agg2 : float[32N]      @ 33N
// agg3 : float[16N]      @ 65N
// row  : int  [N]        @ 81N   CSR start (global index into pay)
// dgar : int  [N]        @ 82N   in-degree (real edges)
// bcnt : int  [NB]       @ 83N
// gsum : float[G]        @ 83N+NB
// gcnt : int  [G]        @ +G
// pay  : uint [NB*CAP]   @ +G    packed (src | local_dst<<17), dst-sorted
// total ≈ 11.97M units ≈ 47.9 MB

__global__ void k_zero(int* __restrict__ bcnt, float* __restrict__ gsum,
                       int* __restrict__ gcnt) {
    int i = blockIdx.x * blockDim.x + threadIdx.x;
    if (i < NB) bcnt[i] = 0;
    if (i < N_GRAPHS) { gsum[i] = 0.0f; gcnt[i] = 0; }
}

// two-level bucketize by dst: LDS histogram -> scan -> LDS place -> run flush
__global__ __launch_bounds__(256) void k_bucket(
    const int* __restrict__ src, const int* __restrict__ dst,
    int* __restrict__ bcnt, unsigned* __restrict__ pay) {
    __shared__ int cnt[NB];
    __shared__ int off[NB];
    __shared__ int scanbuf[256];
    __shared__ unsigned rec[EPB];

    int tid = threadIdx.x;
    int e0 = blockIdx.x * EPB;
    for (int i = tid; i < NB; i += 256) cnt[i] = 0;
    __syncthreads();

#pragma unroll
    for (int k = 0; k < EPB / 256; ++k) {
        int e = e0 + k * 256 + tid;
        if (e < N_EDGES) atomicAdd(&cnt[(unsigned)dst[e] / NPB], 1);
    }
    __syncthreads();

    int base = tid * 4;
    int c0 = cnt[base], c1 = cnt[base + 1], c2 = cnt[base + 2], c3 = cnt[base + 3];
    int part = c0 + c1 + c2 + c3;
    scanbuf[tid] = part;
    __syncthreads();
    for (int o = 1; o < 256; o <<= 1) {
        int v = (tid >= o) ? scanbuf[tid - o] : 0;
        __syncthreads();
        scanbuf[tid] += v;
        __syncthreads();
    }
    int ex = scanbuf[tid] - part;
    off[base]     = ex;
    off[base + 1] = ex + c0;
    off[base + 2] = ex + c0 + c1;
    off[base + 3] = ex + c0 + c1 + c2;
    __syncthreads();

#pragma unroll
    for (int k = 0; k < EPB / 256; ++k) {
        int e = e0 + k * 256 + tid;
        if (e < N_EDGES) {
            unsigned s = (unsigned)src[e];
            unsigned d = (unsigned)dst[e];
            unsigned b = d / NPB;
            unsigned ld = d - b * NPB;
            int p = atomicAdd(&off[b], 1);
            rec[p] = s | (ld << 17);
        }
    }
    __syncthreads();

    for (int b = tid; b < NB; b += 256) {
        int c = cnt[b];
        if (c == 0) continue;
        int ls = off[b] - c;
        int gb = atomicAdd(&bcnt[b], c);
        unsigned* dstp = pay + (size_t)b * CAP;
        for (int k = 0; k < c; ++k) {
            int gp = gb + k;
            if (gp < CAP) dstp[gp] = rec[ls + k];
        }
    }
}

// per-bucket: counting-sort records by LOCAL DST -> CSR; write row/deg;
// fused k_prep (dinv + pre-scaled xp) from the dst histogram.
__global__ __launch_bounds__(256) void k_sort(
    unsigned* __restrict__ pay, const int* __restrict__ bcnt,
    const float* __restrict__ x, float* __restrict__ dinv,
    float* __restrict__ xp, int* __restrict__ row, int* __restrict__ dgar) {
    __shared__ unsigned rec[CAP], rec2[CAP];
    __shared__ int hl[NPB], st[NPB], ofl[NPB];
    int tid = threadIdx.x;
    int b = blockIdx.x;
    int cnt = bcnt[b]; if (cnt > CAP) cnt = CAP;
    unsigned* P = pay + (size_t)b * CAP;

    if (tid < NPB) hl[tid] = 0;
    __syncthreads();

    for (int i = tid; i < cnt; i += 256) {
        unsigned w = P[i];
        rec[i] = w;
        atomicAdd(&hl[w >> 17], 1);
    }
    __syncthreads();

    if (tid == 0) {
        int run = 0;
        for (int l = 0; l < NPB; ++l) { st[l] = run; run += hl[l]; }
    }
    __syncthreads();
    if (tid < NPB) ofl[tid] = st[tid];

    // CSR metadata + fused prep for this bucket's own nodes
    if (tid < NPB) {
        int n = b * NPB + tid;
        if (n < N_NODES) {
            row[n]  = b * CAP + st[tid];
            dgar[n] = hl[tid];
            float di = rsqrtf((float)(hl[tid] + 1));   // +1 self-loop
            dinv[n] = di;
            float4 v = reinterpret_cast<const float4*>(x)[n];
            v.x *= di; v.y *= di; v.z *= di; v.w *= di;
            reinterpret_cast<float4*>(xp)[n] = v;
        }
    }
    __syncthreads();

    for (int i = tid; i < cnt; i += 256) {
        unsigned w = rec[i];
        int p = atomicAdd(&ofl[w >> 17], 1);
        rec2[p] = w;
    }
    __syncthreads();

    for (int i = tid; i < cnt; i += 256) P[i] = rec2[i];
}

// L1 gather: 4 lanes/node, scalar register accumulate, no LDS
__global__ __launch_bounds__(256) void k_g1(
    const float* __restrict__ xp, const unsigned* __restrict__ pay,
    const int* __restrict__ row, const int* __restrict__ dgar,
    float* __restrict__ agg1) {
    int tid = threadIdx.x;
    int lane = tid & 3;
    int n = blockIdx.x * 64 + (tid >> 2);
    if (n >= N_NODES) return;
    int r = row[n], d = dgar[n];
    const unsigned* P = pay + r;
    float acc = 0.0f;
#pragma unroll 4
    for (int j = 0; j < d; ++j) {
        int sn = P[j] & 0x1FFFF;
        acc += xp[sn * 4 + lane];
    }
    agg1[(size_t)n * 4 + lane] = acc;
}

// finish L1: a=(agg1+self)*dinv -> relu(@W1+b1) -> @W2 -> *dinv -> t2ph (fp16)
__global__ __launch_bounds__(256) void k_dense1(
    const float* __restrict__ agg1, const float* __restrict__ xp,
    const float* __restrict__ dinv,
    const float* __restrict__ W1, const float* __restrict__ b1,
    const float* __restrict__ W2, __half* __restrict__ t2ph) {
    __shared__ float sW1[256], sb1[64], sW2[2048];
    int tid = threadIdx.x;
    sW1[tid] = W1[tid];
    if (tid < 64) sb1[tid] = b1[tid];
    for (int i = tid; i < 2048; i += 256) sW2[i] = W2[i];
    __syncthreads();

    int n = blockIdx.x * 256 + tid;
    if (n >= N_NODES) return;
    float di = dinv[n];
    float4 ag = reinterpret_cast<const float4*>(agg1)[n];
    float4 sv = reinterpret_cast<const float4*>(xp)[n];
    float a[4] = {(ag.x + sv.x) * di, (ag.y + sv.y) * di,
                  (ag.z + sv.z) * di, (ag.w + sv.w) * di};
    float t[32];
#pragma unroll
    for (int k = 0; k < 32; ++k) t[k] = 0.0f;
    for (int j = 0; j < 64; ++j) {
        float h = sb1[j];
#pragma unroll
        for (int i = 0; i < 4; ++i) h += a[i] * sW1[i * 64 + j];
        h = fmaxf(h, 0.0f);
#pragma unroll
        for (int k = 0; k < 32; ++k) t[k] += h * sW2[j * 32 + k];
    }
    __half2* o = reinterpret_cast<__half2*>(t2ph + (size_t)n * 32);
#pragma unroll
    for (int q = 0; q < 16; ++q)
        o[q] = __floats2half2_rn(t[2*q] * di, t[2*q+1] * di);
}

// L2 gather: 4 lanes/node x 16B (8 fp16) per edge, register accumulate
__global__ __launch_bounds__(256) void k_g2(
    const __half* __restrict__ t2ph, const unsigned* __restrict__ pay,
    const int* __restrict__ row, const int* __restrict__ dgar,
    float* __restrict__ agg2) {
    int tid = threadIdx.x;
    int lane = tid & 3;
    int n = blockIdx.x * 64 + (tid >> 2);
    if (n >= N_NODES) return;
    int r = row[n], d = dgar[n];
    const unsigned* P = pay + r;
    float a0 = 0, a1 = 0, a2 = 0, a3 = 0, a4 = 0, a5 = 0, a6 = 0, a7 = 0;
#pragma unroll 4
    for (int j = 0; j < d; ++j) {
        int sn = P[j] & 0x1FFFF;
        union { uint4 u; __half2 h[4]; } U;
        U.u = *reinterpret_cast<const uint4*>(t2ph + (size_t)sn * 32 + lane * 8);
        float2 f0 = __half22float2(U.h[0]);
        float2 f1 = __half22float2(U.h[1]);
        float2 f2 = __half22float2(U.h[2]);
        float2 f3 = __half22float2(U.h[3]);
        a0 += f0.x; a1 += f0.y; a2 += f1.x; a3 += f1.y;
        a4 += f2.x; a5 += f2.y; a6 += f3.x; a7 += f3.y;
    }
    float4* o = reinterpret_cast<float4*>(agg2 + (size_t)n * 32 + lane * 8);
    o[0] = make_float4(a0, a1, a2, a3);
    o[1] = make_float4(a4, a5, a6, a7);
}

// finish L2: h=relu((agg2+self)*dinv+b2) -> @W3 -> *dinv -> t3ph (fp16)
__global__ __launch_bounds__(256) void k_dense2(
    const float* __restrict__ agg2, const __half* __restrict__ t2ph,
    const float* __restrict__ dinv,
    const float* __restrict__ b2, const float* __restrict__ W3,
    __half* __restrict__ t3ph) {
    __shared__ float sb2[32], sW3[512];
    int tid = threadIdx.x;
    if (tid < 32) sb2[tid] = b2[tid];
    for (int i = tid; i < 512; i += 256) sW3[i] = W3[i];
    __syncthreads();

    int n = blockIdx.x * 256 + tid;
    if (n >= N_NODES) return;
    float di = dinv[n];
    const float2* ag = reinterpret_cast<const float2*>(agg2 + (size_t)n * 32);
    const __half2* sp = reinterpret_cast<const __half2*>(t2ph + (size_t)n * 32);
    float h[32];
#pragma unroll
    for (int q = 0; q < 16; ++q) {
        float2 a = ag[q];
        float2 sv = __half22float2(sp[q]);
        h[2*q]   = fmaxf((a.x + sv.x) * di + sb2[2*q],   0.0f);
        h[2*q+1] = fmaxf((a.y + sv.y) * di + sb2[2*q+1], 0.0f);
    }
    float t[16];
#pragma unroll
    for (int k = 0; k < 16; ++k) t[k] = 0.0f;
    for (int j = 0; j < 32; ++j) {
#pragma unroll
        for (int k = 0; k < 16; ++k) t[k] += h[j] * sW3[j * 16 + k];
    }
    __half2* o = reinterpret_cast<__half2*>(t3ph + (size_t)n * 16);
#pragma unroll
    for (int q = 0; q < 8; ++q)
        o[q] = __floats2half2_rn(t[2*q] * di, t[2*q+1] * di);
}

// L3 gather: 4 lanes/node x 8B (4 fp16) per edge
__global__ __launch_bounds__(256) void k_g3(
    const __half* __restrict__ t3ph, const unsigned* __restrict__ pay,
    const int* __restrict__ row, const int* __restrict__ dgar,
    float* __restrict__ agg3) {
    int tid = threadIdx.x;
    int lane = tid & 3;
    int n = blockIdx.x * 64 + (tid >> 2);
    if (n >= N_NODES) return;
    int r = row[n], d = dgar[n];
    const unsigned* P = pay + r;
    float a0 = 0, a1 = 0, a2 = 0, a3 = 0;
#pragma unroll 4
    for (int j = 0; j < d; ++j) {
        int sn = P[j] & 0x1FFFF;
        union { uint2 u; __half2 h[2]; } U;
        U.u = *reinterpret_cast<const uint2*>(t3ph + (size_t)sn * 16 + lane * 4);
        float2 f0 = __half22float2(U.h[0]);
        float2 f1 = __half22float2(U.h[1]);
        a0 += f0.x; a1 += f0.y; a2 += f1.x; a3 += f1.y;
    }
    *reinterpret_cast<float4*>(agg3 + (size_t)n * 16 + lane * 4) =
        make_float4(a0, a1, a2, a3);
}

// finish L3 (+self, +b3), fuse 16->1 head dot and mean-pool segment-sum
__global__ void k_pool(const float* __restrict__ agg3, const __half* __restrict__ t3ph,
                       const float* __restrict__ dinv,
                       const float* __restrict__ b3, const float* __restrict__ Wl,
                       const int* __restrict__ batch,
                       float* __restrict__ gsum, int* __restrict__ gcnt) {
    int n = blockIdx.x * blockDim.x + threadIdx.x;
    if (n >= N_NODES) return;
    float di = dinv[n];
    const float2* ag = reinterpret_cast<const float2*>(agg3 + (size_t)n * 16);
    const __half2* sp = reinterpret_cast<const __half2*>(t3ph + (size_t)n * 16);
    float s = 0.0f;
#pragma unroll
    for (int q = 0; q < 8; ++q) {
        float2 a = ag[q];
        float2 sv = __half22float2(sp[q]);
        s += ((a.x + sv.x) * di + b3[2*q])   * Wl[2*q];
        s += ((a.y + sv.y) * di + b3[2*q+1]) * Wl[2*q+1];
    }
    int g = batch[n];
    atomicAdd(&gsum[g], s);
    atomicAdd(&gcnt[g], 1);
}

__global__ void k_head(const float* __restrict__ gsum, const int* __restrict__ gcnt,
                       const float* __restrict__ bl, float* __restrict__ out) {
    int g = blockIdx.x * blockDim.x + threadIdx.x;
    if (g >= N_GRAPHS) return;
    float c = fmaxf((float)gcnt[g], 1.0f);
    out[g] = fmaxf(gsum[g] / c + bl[0], 0.0f);
}

extern "C" void kernel_launch(void* const* d_in, const int* in_sizes, int n_in,
                              void* d_out, int out_size, void* d_ws, size_t ws_size,
                              hipStream_t stream) {
    const float* x  = (const float*)d_in[0];
    const float* W1 = (const float*)d_in[1];
    const float* b1 = (const float*)d_in[2];
    const float* W2 = (const float*)d_in[3];
    const float* b2 = (const float*)d_in[4];
    const float* W3 = (const float*)d_in[5];
    const float* b3 = (const float*)d_in[6];
    const float* Wl = (const float*)d_in[7];
    const float* bl = (const float*)d_in[8];
    const int*   ei = (const int*)d_in[9];        // [2, E] row-major
    const int* batch = (const int*)d_in[10];
    const int* src = ei;
    const int* dst = ei + N_EDGES;
    float* out = (float*)d_out;

    const size_t N = N_NODES, G = N_GRAPHS;
    char* ws = (char*)d_ws;
    float*    dinv = (float*)   (ws);
    float*    xp   = (float*)   (ws + 4 * (N));
    __half*   t2ph = (__half*)  (ws + 4 * (5 * N));
    __half*   t3ph = (__half*)  (ws + 4 * (21 * N));
    float*    agg1 = (float*)   (ws + 4 * (29 * N));
    float*    agg2 = (float*)   (ws + 4 * (33 * N));
    float*    agg3 = (float*)   (ws + 4 * (65 * N));
    int*      row  = (int*)     (ws + 4 * (81 * N));
    int*      dgar = (int*)     (ws + 4 * (82 * N));
    int*      bcnt = (int*)     (ws + 4 * (83 * N));
    float*    gsum = (float*)   (ws + 4 * (83 * N + NB));
    int*      gcnt = (int*)     (ws + 4 * (83 * N + NB + G));
    unsigned* pay  = (unsigned*)(ws + 4 * (83 * N + NB + 2 * G));

    const int B = 256;
    const int gN = (N_NODES + B - 1) / B;            // 391
    const int gB = (N_EDGES + EPB - 1) / EPB;        // 391
    const int gG = (N_NODES + 63) / 64;              // 1563

    k_zero  <<<gN, B, 0, stream>>>(bcnt, gsum, gcnt);
    k_bucket<<<gB, B, 0, stream>>>(src, dst, bcnt, pay);
    k_sort  <<<NB, B, 0, stream>>>(pay, bcnt, x, dinv, xp, row, dgar);
    k_g1    <<<gG, B, 0, stream>>>(xp, pay, row, dgar, agg1);
    k_dense1<<<gN, B, 0, stream>>>(agg1, xp, dinv, W1, b1, W2, t2ph);
    k_g2    <<<gG, B, 0, stream>>>(t2ph, pay, row, dgar, agg2);
    k_dense2<<<gN, B, 0, stream>>>(agg2, t2ph, dinv, b2, W3, t3ph);
    k_g3    <<<gG, B, 0, stream>>>(t3ph, pay, row, dgar, agg3);
    k_pool  <<<gN, B, 0, stream>>>(agg3, t3ph, dinv, b3, Wl, batch, gsum, gcnt);
    k_head  <<<(N_GRAPHS + B - 1) / B, B, 0, stream>>>(gsum, gcnt, bl, out);
}

// Round 14
// 272.272 us; speedup vs baseline: 4.5020x; 1.2063x over previous
//
#include <hip/hip_runtime.h>
#include <hip/hip_fp16.h>

#define N_NODES 100000
#define N_EDGES 3200000
#define N_GRAPHS 1000
#define NB 1024            // dst-range buckets
#define NPB 98             // nodes per bucket
#define CAP 3584           // per-bucket edge capacity (mean 3136 + 8 sigma)
#define EPB 8192           // edges per bucketing block

// ---------------- workspace layout (element offsets, 4B units) --------------
// dinv : float[N]        @ 0
// xp   : float[4N]       @ N
// t2ph : half [32N]      @ 5N    (16N units)
// t3ph : half [16N]      @ 21N   (8N units)
// agg1 : float[4N]       @ 29N
// agg2 : float[32N]      @ 33N
// sval : float[N]        @ 65N   per-node head scalar
// row  : int  [N]        @ 81N   CSR start (global index into pay)
// dgar : int  [N]        @ 82N   in-degree (real edges)
// bcnt : int  [NB]       @ 83N
// pay  : uint [NB*CAP]   @ 83N+NB   packed (src | local_dst<<17), dst-sorted
// total ≈ 12.0M units ≈ 48 MB

__global__ void k_zero(int* __restrict__ bcnt) {
    int i = blockIdx.x * blockDim.x + threadIdx.x;
    if (i < NB) bcnt[i] = 0;
}

// two-level bucketize by dst: LDS histogram -> scan -> LDS place -> run flush
__global__ __launch_bounds__(256) void k_bucket(
    const int* __restrict__ src, const int* __restrict__ dst,
    int* __restrict__ bcnt, unsigned* __restrict__ pay) {
    __shared__ int cnt[NB];
    __shared__ int off[NB];
    __shared__ int scanbuf[256];
    __shared__ unsigned rec[EPB];

    int tid = threadIdx.x;
    int e0 = blockIdx.x * EPB;
    for (int i = tid; i < NB; i += 256) cnt[i] = 0;
    __syncthreads();

#pragma unroll
    for (int k = 0; k < EPB / 256; ++k) {
        int e = e0 + k * 256 + tid;
        if (e < N_EDGES) atomicAdd(&cnt[(unsigned)dst[e] / NPB], 1);
    }
    __syncthreads();

    int base = tid * 4;
    int c0 = cnt[base], c1 = cnt[base + 1], c2 = cnt[base + 2], c3 = cnt[base + 3];
    int part = c0 + c1 + c2 + c3;
    scanbuf[tid] = part;
    __syncthreads();
    for (int o = 1; o < 256; o <<= 1) {
        int v = (tid >= o) ? scanbuf[tid - o] : 0;
        __syncthreads();
        scanbuf[tid] += v;
        __syncthreads();
    }
    int ex = scanbuf[tid] - part;
    off[base]     = ex;
    off[base + 1] = ex + c0;
    off[base + 2] = ex + c0 + c1;
    off[base + 3] = ex + c0 + c1 + c2;
    __syncthreads();

#pragma unroll
    for (int k = 0; k < EPB / 256; ++k) {
        int e = e0 + k * 256 + tid;
        if (e < N_EDGES) {
            unsigned s = (unsigned)src[e];
            unsigned d = (unsigned)dst[e];
            unsigned b = d / NPB;
            unsigned ld = d - b * NPB;
            int p = atomicAdd(&off[b], 1);
            rec[p] = s | (ld << 17);
        }
    }
    __syncthreads();

    for (int b = tid; b < NB; b += 256) {
        int c = cnt[b];
        if (c == 0) continue;
        int ls = off[b] - c;
        int gb = atomicAdd(&bcnt[b], c);
        unsigned* dstp = pay + (size_t)b * CAP;
        for (int k = 0; k < c; ++k) {
            int gp = gb + k;
            if (gp < CAP) dstp[gp] = rec[ls + k];
        }
    }
}

// per-bucket: counting-sort records by LOCAL DST -> CSR; write row/deg;
// fused k_prep (dinv + pre-scaled xp) from the dst histogram.
__global__ __launch_bounds__(256) void k_sort(
    unsigned* __restrict__ pay, const int* __restrict__ bcnt,
    const float* __restrict__ x, float* __restrict__ dinv,
    float* __restrict__ xp, int* __restrict__ row, int* __restrict__ dgar) {
    __shared__ unsigned rec[CAP], rec2[CAP];
    __shared__ int hl[NPB], st[NPB], ofl[NPB];
    int tid = threadIdx.x;
    int b = blockIdx.x;
    int cnt = bcnt[b]; if (cnt > CAP) cnt = CAP;
    unsigned* P = pay + (size_t)b * CAP;

    if (tid < NPB) hl[tid] = 0;
    __syncthreads();

    for (int i = tid; i < cnt; i += 256) {
        unsigned w = P[i];
        rec[i] = w;
        atomicAdd(&hl[w >> 17], 1);
    }
    __syncthreads();

    if (tid == 0) {
        int run = 0;
        for (int l = 0; l < NPB; ++l) { st[l] = run; run += hl[l]; }
    }
    __syncthreads();
    if (tid < NPB) ofl[tid] = st[tid];

    // CSR metadata + fused prep for this bucket's own nodes
    if (tid < NPB) {
        int n = b * NPB + tid;
        if (n < N_NODES) {
            row[n]  = b * CAP + st[tid];
            dgar[n] = hl[tid];
            float di = rsqrtf((float)(hl[tid] + 1));   // +1 self-loop
            dinv[n] = di;
            float4 v = reinterpret_cast<const float4*>(x)[n];
            v.x *= di; v.y *= di; v.z *= di; v.w *= di;
            reinterpret_cast<float4*>(xp)[n] = v;
        }
    }
    __syncthreads();

    for (int i = tid; i < cnt; i += 256) {
        unsigned w = rec[i];
        int p = atomicAdd(&ofl[w >> 17], 1);
        rec2[p] = w;
    }
    __syncthreads();

    for (int i = tid; i < cnt; i += 256) P[i] = rec2[i];
}

// L1 gather: 4 lanes/node, scalar register accumulate, no LDS
__global__ __launch_bounds__(256) void k_g1(
    const float* __restrict__ xp, const unsigned* __restrict__ pay,
    const int* __restrict__ row, const int* __restrict__ dgar,
    float* __restrict__ agg1) {
    int tid = threadIdx.x;
    int lane = tid & 3;
    int n = blockIdx.x * 64 + (tid >> 2);
    if (n >= N_NODES) return;
    int r = row[n], d = dgar[n];
    const unsigned* P = pay + r;
    float acc = 0.0f;
#pragma unroll 4
    for (int j = 0; j < d; ++j) {
        int sn = P[j] & 0x1FFFF;
        acc += xp[sn * 4 + lane];
    }
    agg1[(size_t)n * 4 + lane] = acc;
}

// finish L1: a=(agg1+self)*dinv -> relu(@W1+b1) -> @W2 -> *dinv -> t2ph (fp16)
__global__ __launch_bounds__(256) void k_dense1(
    const float* __restrict__ agg1, const float* __restrict__ xp,
    const float* __restrict__ dinv,
    const float* __restrict__ W1, const float* __restrict__ b1,
    const float* __restrict__ W2, __half* __restrict__ t2ph) {
    __shared__ float sW1[256], sb1[64], sW2[2048];
    int tid = threadIdx.x;
    sW1[tid] = W1[tid];
    if (tid < 64) sb1[tid] = b1[tid];
    for (int i = tid; i < 2048; i += 256) sW2[i] = W2[i];
    __syncthreads();

    int n = blockIdx.x * 256 + tid;
    if (n >= N_NODES) return;
    float di = dinv[n];
    float4 ag = reinterpret_cast<const float4*>(agg1)[n];
    float4 sv = reinterpret_cast<const float4*>(xp)[n];
    float a[4] = {(ag.x + sv.x) * di, (ag.y + sv.y) * di,
                  (ag.z + sv.z) * di, (ag.w + sv.w) * di};
    float t[32];
#pragma unroll
    for (int k = 0; k < 32; ++k) t[k] = 0.0f;
    for (int j = 0; j < 64; ++j) {
        float h = sb1[j];
#pragma unroll
        for (int i = 0; i < 4; ++i) h += a[i] * sW1[i * 64 + j];
        h = fmaxf(h, 0.0f);
#pragma unroll
        for (int k = 0; k < 32; ++k) t[k] += h * sW2[j * 32 + k];
    }
    __half2* o = reinterpret_cast<__half2*>(t2ph + (size_t)n * 32);
#pragma unroll
    for (int q = 0; q < 16; ++q)
        o[q] = __floats2half2_rn(t[2*q] * di, t[2*q+1] * di);
}

// L2 gather: 4 lanes/node x 16B (8 fp16) per edge, register accumulate
__global__ __launch_bounds__(256) void k_g2(
    const __half* __restrict__ t2ph, const unsigned* __restrict__ pay,
    const int* __restrict__ row, const int* __restrict__ dgar,
    float* __restrict__ agg2) {
    int tid = threadIdx.x;
    int lane = tid & 3;
    int n = blockIdx.x * 64 + (tid >> 2);
    if (n >= N_NODES) return;
    int r = row[n], d = dgar[n];
    const unsigned* P = pay + r;
    float a0 = 0, a1 = 0, a2 = 0, a3 = 0, a4 = 0, a5 = 0, a6 = 0, a7 = 0;
#pragma unroll 4
    for (int j = 0; j < d; ++j) {
        int sn = P[j] & 0x1FFFF;
        union { uint4 u; __half2 h[4]; } U;
        U.u = *reinterpret_cast<const uint4*>(t2ph + (size_t)sn * 32 + lane * 8);
        float2 f0 = __half22float2(U.h[0]);
        float2 f1 = __half22float2(U.h[1]);
        float2 f2 = __half22float2(U.h[2]);
        float2 f3 = __half22float2(U.h[3]);
        a0 += f0.x; a1 += f0.y; a2 += f1.x; a3 += f1.y;
        a4 += f2.x; a5 += f2.y; a6 += f3.x; a7 += f3.y;
    }
    float4* o = reinterpret_cast<float4*>(agg2 + (size_t)n * 32 + lane * 8);
    o[0] = make_float4(a0, a1, a2, a3);
    o[1] = make_float4(a4, a5, a6, a7);
}

// finish L2: h=relu((agg2+self)*dinv+b2) -> @W3 -> *dinv -> t3ph (fp16)
__global__ __launch_bounds__(256) void k_dense2(
    const float* __restrict__ agg2, const __half* __restrict__ t2ph,
    const float* __restrict__ dinv,
    const float* __restrict__ b2, const float* __restrict__ W3,
    __half* __restrict__ t3ph) {
    __shared__ float sb2[32], sW3[512];
    int tid = threadIdx.x;
    if (tid < 32) sb2[tid] = b2[tid];
    for (int i = tid; i < 512; i += 256) sW3[i] = W3[i];
    __syncthreads();

    int n = blockIdx.x * 256 + tid;
    if (n >= N_NODES) return;
    float di = dinv[n];
    const float2* ag = reinterpret_cast<const float2*>(agg2 + (size_t)n * 32);
    const __half2* sp = reinterpret_cast<const __half2*>(t2ph + (size_t)n * 32);
    float h[32];
#pragma unroll
    for (int q = 0; q < 16; ++q) {
        float2 a = ag[q];
        float2 sv = __half22float2(sp[q]);
        h[2*q]   = fmaxf((a.x + sv.x) * di + sb2[2*q],   0.0f);
        h[2*q+1] = fmaxf((a.y + sv.y) * di + sb2[2*q+1], 0.0f);
    }
    float t[16];
#pragma unroll
    for (int k = 0; k < 16; ++k) t[k] = 0.0f;
    for (int j = 0; j < 32; ++j) {
#pragma unroll
        for (int k = 0; k < 16; ++k) t[k] += h[j] * sW3[j * 16 + k];
    }
    __half2* o = reinterpret_cast<__half2*>(t3ph + (size_t)n * 16);
#pragma unroll
    for (int q = 0; q < 8; ++q)
        o[q] = __floats2half2_rn(t[2*q] * di, t[2*q+1] * di);
}

// L3 gather + fused L3 finish + head dot: 4 lanes/node x 8B per edge.
// After accumulation, each 4-lane group holds all 16 feats of node n:
// s = sum_q ((agg_q + self_q)*dinv + b3_q)*Wl_q  via shfl_xor reduce.
__global__ __launch_bounds__(256) void k_g3(
    const __half* __restrict__ t3ph, const unsigned* __restrict__ pay,
    const int* __restrict__ row, const int* __restrict__ dgar,
    const float* __restrict__ dinv, const float* __restrict__ b3,
    const float* __restrict__ Wl, float* __restrict__ sval) {
    int tid = threadIdx.x;
    int lane = tid & 3;
    int n = blockIdx.x * 64 + (tid >> 2);
    if (n >= N_NODES) return;
    int r = row[n], d = dgar[n];
    const unsigned* P = pay + r;
    float a0 = 0, a1 = 0, a2 = 0, a3 = 0;
#pragma unroll 4
    for (int j = 0; j < d; ++j) {
        int sn = P[j] & 0x1FFFF;
        union { uint2 u; __half2 h[2]; } U;
        U.u = *reinterpret_cast<const uint2*>(t3ph + (size_t)sn * 16 + lane * 4);
        float2 f0 = __half22float2(U.h[0]);
        float2 f1 = __half22float2(U.h[1]);
        a0 += f0.x; a1 += f0.y; a2 += f1.x; a3 += f1.y;
    }
    union { uint2 u; __half2 h[2]; } S;
    S.u = *reinterpret_cast<const uint2*>(t3ph + (size_t)n * 16 + lane * 4);
    float2 s0 = __half22float2(S.h[0]);
    float2 s1 = __half22float2(S.h[1]);
    float di = dinv[n];
    float p = ((a0 + s0.x) * di + b3[lane * 4 + 0]) * Wl[lane * 4 + 0]
            + ((a1 + s0.y) * di + b3[lane * 4 + 1]) * Wl[lane * 4 + 1]
            + ((a2 + s1.x) * di + b3[lane * 4 + 2]) * Wl[lane * 4 + 2]
            + ((a3 + s1.y) * di + b3[lane * 4 + 3]) * Wl[lane * 4 + 3];
    p += __shfl_xor(p, 1);
    p += __shfl_xor(p, 2);
    if (lane == 0) sval[n] = p;
}

// mean-pool + head per graph: one wave per graph; binary-search the sorted
// batch array for [start,end), strided sum of sval, shfl reduce. No atomics.
__global__ __launch_bounds__(64) void k_poolg(
    const float* __restrict__ sval, const int* __restrict__ batch,
    const float* __restrict__ bl, float* __restrict__ out) {
    int g = blockIdx.x;
    int lo = 0, hi = N_NODES;
    while (lo < hi) { int m = (lo + hi) >> 1; if (batch[m] < g) lo = m + 1; else hi = m; }
    int s0 = lo;
    hi = N_NODES;
    while (lo < hi) { int m = (lo + hi) >> 1; if (batch[m] < g + 1) lo = m + 1; else hi = m; }
    int s1 = lo;
    float s = 0.0f;
    for (int i = s0 + threadIdx.x; i < s1; i += 64) s += sval[i];
#pragma unroll
    for (int o = 32; o > 0; o >>= 1) s += __shfl_down(s, o);
    if (threadIdx.x == 0) {
        float c = fmaxf((float)(s1 - s0), 1.0f);
        out[g] = fmaxf(s / c + bl[0], 0.0f);
    }
}

extern "C" void kernel_launch(void* const* d_in, const int* in_sizes, int n_in,
                              void* d_out, int out_size, void* d_ws, size_t ws_size,
                              hipStream_t stream) {
    const float* x  = (const float*)d_in[0];
    const float* W1 = (const float*)d_in[1];
    const float* b1 = (const float*)d_in[2];
    const float* W2 = (const float*)d_in[3];
    const float* b2 = (const float*)d_in[4];
    const float* W3 = (const float*)d_in[5];
    const float* b3 = (const float*)d_in[6];
    const float* Wl = (const float*)d_in[7];
    const float* bl = (const float*)d_in[8];
    const int*   ei = (const int*)d_in[9];        // [2, E] row-major
    const int* batch = (const int*)d_in[10];
    const int* src = ei;
    const int* dst = ei + N_EDGES;
    float* out = (float*)d_out;

    const size_t N = N_NODES;
    char* ws = (char*)d_ws;
    float*    dinv = (float*)   (ws);
    float*    xp   = (float*)   (ws + 4 * (N));
    __half*   t2ph = (__half*)  (ws + 4 * (5 * N));
    __half*   t3ph = (__half*)  (ws + 4 * (21 * N));
    float*    agg1 = (float*)   (ws + 4 * (29 * N));
    float*    agg2 = (float*)   (ws + 4 * (33 * N));
    float*    sval = (float*)   (ws + 4 * (65 * N));
    int*      row  = (int*)     (ws + 4 * (81 * N));
    int*      dgar = (int*)     (ws + 4 * (82 * N));
    int*      bcnt = (int*)     (ws + 4 * (83 * N));
    unsigned* pay  = (unsigned*)(ws + 4 * (83 * N + NB));

    const int B = 256;
    const int gN = (N_NODES + B - 1) / B;            // 391
    const int gB = (N_EDGES + EPB - 1) / EPB;        // 391
    const int gG = (N_NODES + 63) / 64;              // 1563

    k_zero  <<<(NB + B - 1) / B, B, 0, stream>>>(bcnt);
    k_bucket<<<gB, B, 0, stream>>>(src, dst, bcnt, pay);
    k_sort  <<<NB, B, 0, stream>>>(pay, bcnt, x, dinv, xp, row, dgar);
    k_g1    <<<gG, B, 0, stream>>>(xp, pay, row, dgar, agg1);
    k_dense1<<<gN, B, 0, stream>>>(agg1, xp, dinv, W1, b1, W2, t2ph);
    k_g2    <<<gG, B, 0, stream>>>(t2ph, pay, row, dgar, agg2);
    k_dense2<<<gN, B, 0, stream>>>(agg2, t2ph, dinv, b2, W3, t3ph);
    k_g3    <<<gG, B, 0, stream>>>(t3ph, pay, row, dgar, dinv, b3, Wl, sval);
    k_poolg <<<N_GRAPHS, 64, 0, stream>>>(sval, batch, bl, out);
}